// Round 2
// baseline (477.460 us; speedup 1.0000x reference)
//
#include <hip/hip_runtime.h>
#include <hip/hip_bf16.h>

// Problem constants
#define NH      12
#define HD      64
#define HID     768
#define B_      2
#define D_      16
#define QL      32
#define SL      512
#define SEQ     545          // 1 + 32 + 512 tokens per (b,d)
#define RPB     8225         // rows per batch: 1 + 32 + 16*512
#define TOT_ROWS 16450
#define PAD_ROWS 16512       // 129*128
#define VT_R    8256         // Vt rows per batch (cls=0, query 1..32, doc d at 40+d*512)
#define WSZ     589824       // 768*768
#define SCALE_  0.125f
#define LOG2E   1.4426950408889634f

typedef __attribute__((ext_vector_type(8))) short short8;
typedef __attribute__((ext_vector_type(4))) short short4v;
typedef __attribute__((ext_vector_type(4))) float float4v;

__device__ __forceinline__ short f2bf(float f) {
    __hip_bfloat16 h = __float2bfloat16(f);
    short s;
    __builtin_memcpy(&s, &h, 2);
    return s;
}

// async global->LDS, 16B per lane; LDS dest = wave-uniform base + lane*16
__device__ __forceinline__ void gl2lds16(const short* g, short* l) {
    __builtin_amdgcn_global_load_lds(
        (const __attribute__((address_space(1))) void*)g,
        (__attribute__((address_space(3))) void*)l, 16, 0, 0);
}

// ---------------------------------------------------------------------------
// Kernel 1: gather cls/query/doc fp32 -> contiguous bf16 X [PAD_ROWS x 768]
// ---------------------------------------------------------------------------
__global__ __launch_bounds__(256) void pack_kernel(
    const float* __restrict__ cls, const float* __restrict__ query,
    const float* __restrict__ doc, short* __restrict__ X)
{
    int idx = (blockIdx.x * 256 + threadIdx.x) * 4;
    int row = idx / HID;
    int col = idx - row * HID;
    float4 v = make_float4(0.f, 0.f, 0.f, 0.f);
    if (row < TOT_ROWS) {
        int b = row / RPB;
        int r = row - b * RPB;
        const float* src;
        if (r == 0)        src = cls   + b * HID + col;
        else if (r < 33)   src = query + ((size_t)(b * QL + (r - 1))) * HID + col;
        else               src = doc   + ((size_t)(b * (D_ * SL) + (r - 33))) * HID + col;
        v = *reinterpret_cast<const float4*>(src);
    }
    short4v o;
    o[0] = f2bf(v.x); o[1] = f2bf(v.y); o[2] = f2bf(v.z); o[3] = f2bf(v.w);
    *reinterpret_cast<short4v*>(X + idx) = o;
}

// ---------------------------------------------------------------------------
// Kernel 1b: W fp32 -> bf16 (Wb lives in d_out; attn overwrites it later)
// ---------------------------------------------------------------------------
__global__ __launch_bounds__(256) void wpack_kernel(
    const float* __restrict__ Wq, const float* __restrict__ Wk,
    const float* __restrict__ Wv, short* __restrict__ Wb)
{
    int idx = (blockIdx.x * 256 + threadIdx.x) * 4;
    int z = idx / WSZ;
    int r = idx - z * WSZ;
    const float* src = (z == 0 ? Wq : (z == 1 ? Wk : Wv)) + r;
    float4 v = *reinterpret_cast<const float4*>(src);
    short4v o;
    o[0] = f2bf(v.x); o[1] = f2bf(v.y); o[2] = f2bf(v.z); o[3] = f2bf(v.w);
    *reinterpret_cast<short4v*>(Wb + idx) = o;
}

// ---------------------------------------------------------------------------
// Kernel 2: Y_p = X @ W_p^T + b_p; global_load_lds(16B) staging, unpadded LDS.
// z==2 (V) writes transposed: Vt[b][col][vrow] with doc rows at 40+d*512
// (16B-aligned runs of 8 tokens for attn's direct short8 V-frag loads).
// ---------------------------------------------------------------------------
__global__ __launch_bounds__(256) void proj_gemm2(
    const short* __restrict__ X, const short* __restrict__ Wb,
    const float* __restrict__ bq, const float* __restrict__ bk,
    const float* __restrict__ bv,
    short* __restrict__ Qb, short* __restrict__ Kb, short* __restrict__ Vt)
{
    int zi = blockIdx.z;
    const short* W = Wb + (size_t)zi * WSZ;
    const float* bias = zi == 0 ? bq : (zi == 1 ? bk : bv);

    __shared__ short Xs[128 * 32];
    __shared__ short Ws[128 * 32];

    int tid  = threadIdx.x;
    int lane = tid & 63, wave = tid >> 6;
    int m0 = blockIdx.x * 128, n0 = blockIdx.y * 128;
    int moff = (wave & 1) * 64, noff = (wave >> 1) * 64;
    int lr = lane & 15, lg = lane >> 4, lk = lg * 8;
    int srow = lane >> 2;            // 0..15 within a 16-row chunk
    int sk   = (lane & 3) * 8;       // k-element offset within 32

    float4v acc[4][4];
    for (int mi = 0; mi < 4; ++mi)
        for (int ni = 0; ni < 4; ++ni)
            acc[mi][ni] = (float4v){0.f, 0.f, 0.f, 0.f};

    // staging pointers: chunk ch = wave*2 + i covers rows ch*16..ch*16+15
    const short* xg0 = X + (size_t)(m0 + wave * 32 + srow) * HID + sk;
    const short* xg1 = xg0 + (size_t)16 * HID;
    const short* wg0 = W + (size_t)(n0 + wave * 32 + srow) * HID + sk;
    const short* wg1 = wg0 + (size_t)16 * HID;
    short* xl0 = &Xs[wave * 1024];
    short* xl1 = &Xs[wave * 1024 + 512];
    short* wl0 = &Ws[wave * 1024];
    short* wl1 = &Ws[wave * 1024 + 512];

    for (int kt = 0; kt < 24; ++kt) {
        __syncthreads();
        gl2lds16(xg0, xl0); gl2lds16(xg1, xl1);
        gl2lds16(wg0, wl0); gl2lds16(wg1, wl1);
        xg0 += 32; xg1 += 32; wg0 += 32; wg1 += 32;
        __syncthreads();

        short8 af[4], bf2[4];
        for (int mi = 0; mi < 4; ++mi)
            af[mi]  = *reinterpret_cast<const short8*>(&Xs[(moff + mi * 16 + lr) * 32 + lk]);
        for (int ni = 0; ni < 4; ++ni)
            bf2[ni] = *reinterpret_cast<const short8*>(&Ws[(noff + ni * 16 + lr) * 32 + lk]);
        for (int mi = 0; mi < 4; ++mi)
            for (int ni = 0; ni < 4; ++ni)
                acc[mi][ni] = __builtin_amdgcn_mfma_f32_16x16x32_bf16(
                    af[mi], bf2[ni], acc[mi][ni], 0, 0, 0);
    }

    if (zi < 2) {
        short* Y = zi == 0 ? Qb : Kb;
        for (int ni = 0; ni < 4; ++ni) {
            int gcol = n0 + noff + ni * 16 + lr;
            float bb = bias[gcol];
            for (int mi = 0; mi < 4; ++mi) {
                int grow = m0 + moff + mi * 16 + lg * 4;
                for (int r = 0; r < 4; ++r)
                    Y[(size_t)(grow + r) * HID + gcol] = f2bf(acc[mi][ni][r] + bb);
            }
        }
    } else {
        for (int ni = 0; ni < 4; ++ni) {
            int gcol = n0 + noff + ni * 16 + lr;
            float bb = bias[gcol];
            for (int mi = 0; mi < 4; ++mi) {
                int growb = m0 + moff + mi * 16 + lg * 4;
                for (int r = 0; r < 4; ++r) {
                    int grow = growb + r;
                    if (grow >= TOT_ROWS) continue;
                    int b  = grow >= RPB ? 1 : 0;
                    int rb = grow - b * RPB;
                    int vr = rb < 33 ? rb : rb + 7;    // doc rows at 40+
                    Vt[((size_t)(b * HID + gcol)) * VT_R + vr] = f2bf(acc[mi][ni][r] + bb);
                }
            }
        }
    }
}

// ---------------------------------------------------------------------------
// Kernel 3: flash attention, S^T form. Internal token order: 0..511 doc,
// 512 cls, 513..544 query, 545..575 pad (mask -1e38 -> p=0; reads clamp into
// valid rows so values are finite garbage * 0).
// No LDS staging for K/V (direct global frag loads); only P round-trips
// through per-wave LDS; zero barriers in the K-loop.
// ---------------------------------------------------------------------------
__global__ __launch_bounds__(256) void attn2(
    const short* __restrict__ Qb, const short* __restrict__ Kb,
    const short* __restrict__ Vt,
    const float* __restrict__ qmask, const float* __restrict__ dmask,
    float* __restrict__ out)
{
    __shared__ short Ps[4][16 * 72];
    __shared__ float maskv[576];

    int tid  = threadIdx.x;
    int lane = tid & 63, wave = tid >> 6;
    int qt = blockIdx.x, h = blockIdx.y, bd = blockIdx.z;
    int b = bd >> 4, d = bd & 15;
    int lr = lane & 15, lg = lane >> 4, lk = lg * 8;
    int base = b * RPB;

    for (int i = tid; i < 576; i += 256) {
        float mv;
        if (i < 512)       mv = dmask[(size_t)(b * D_ + d) * SL + i];
        else if (i == 512) mv = 0.f;
        else if (i < 545)  mv = qmask[b * QL + (i - 513)];
        else               mv = -1e38f;
        maskv[i] = mv * LOG2E;
    }
    __syncthreads();

    // Q as B-operand: n = q = lr
    int qtok = qt * 64 + wave * 16 + lr;
    int qrow = qtok < 512 ? base + 33 + d * SL + qtok : base + qtok - 512;
    const short* qp = Qb + (size_t)qrow * HID + h * HD + lk;
    short8 bq0 = *reinterpret_cast<const short8*>(qp);
    short8 bq1 = *reinterpret_cast<const short8*>(qp + 32);

    float m_i = -1e30f, l_i = 0.f;
    float4v o[4];
    for (int nt = 0; nt < 4; ++nt) o[nt] = (float4v){0.f, 0.f, 0.f, 0.f};

    short* pw = Ps[wave];
    const float qs = SCALE_ * LOG2E;
    const short* vb = Vt + (size_t)(b * HID + h * HD) * VT_R;

    for (int kt = 0; kt < 9; ++kt) {
        // S^T tiles: D[m=key][n=q]; A = K-frag (per tile), B = Q-frag (loop-inv)
        float p[4][4];
        for (int nt = 0; nt < 4; ++nt) {
            int tk = kt * 64 + nt * 16 + lr;
            int krow = tk < 512 ? base + 33 + d * SL + tk : base + tk - 512;
            const short* kp = Kb + (size_t)krow * HID + h * HD + lk;
            short8 ak0 = *reinterpret_cast<const short8*>(kp);
            short8 ak1 = *reinterpret_cast<const short8*>(kp + 32);
            float4v z = (float4v){0.f, 0.f, 0.f, 0.f};
            z = __builtin_amdgcn_mfma_f32_16x16x32_bf16(ak0, bq0, z, 0, 0, 0);
            z = __builtin_amdgcn_mfma_f32_16x16x32_bf16(ak1, bq1, z, 0, 0, 0);
            float4v mk = *reinterpret_cast<const float4v*>(&maskv[kt * 64 + nt * 16 + lg * 4]);
            for (int r = 0; r < 4; ++r) p[nt][r] = z[r] * qs + mk[r];
        }

        // softmax (log2 domain), per-lane state for q = lr
        float tmx = p[0][0];
        for (int nt = 0; nt < 4; ++nt)
            for (int r = 0; r < 4; ++r) tmx = fmaxf(tmx, p[nt][r]);
        tmx = fmaxf(tmx, __shfl_xor(tmx, 16));
        tmx = fmaxf(tmx, __shfl_xor(tmx, 32));
        float mnew = fmaxf(m_i, tmx);
        float alpha = exp2f(m_i - mnew);
        m_i = mnew;
        float sum = 0.f;
        for (int nt = 0; nt < 4; ++nt)
            for (int r = 0; r < 4; ++r) {
                p[nt][r] = exp2f(p[nt][r] - mnew);
                sum += p[nt][r];
            }
        sum += __shfl_xor(sum, 16);
        sum += __shfl_xor(sum, 32);
        l_i = l_i * alpha + sum;

        // P[key][q=lr] -> LDS row-major [q][key]: one b64 write per nt
        for (int nt = 0; nt < 4; ++nt) {
            short4v pk;
            for (int r = 0; r < 4; ++r) pk[r] = f2bf(p[nt][r]);
            *reinterpret_cast<short4v*>(&pw[lr * 72 + nt * 16 + lg * 4]) = pk;
        }
        // rescale O (alpha per q = lg*4+r, broadcast from lanes 0..15)
        float al[4];
        for (int r = 0; r < 4; ++r) al[r] = __shfl(alpha, lg * 4 + r);
        for (int nt = 0; nt < 4; ++nt)
            for (int r = 0; r < 4; ++r) o[nt][r] *= al[r];

        short8 ap0 = *reinterpret_cast<const short8*>(&pw[lr * 72 + lk]);
        short8 ap1 = *reinterpret_cast<const short8*>(&pw[lr * 72 + 32 + lk]);

        // V frags direct from Vt: B[n=dim][k=key]
        int t0 = kt * 64 + lk;
        int vr0 = t0 < 512 ? 40 + d * SL + t0 : t0 - 512;
        int t1 = t0 + 32;
        int vr1 = t1 < 512 ? 40 + d * SL + t1 : t1 - 512;
        for (int nt = 0; nt < 4; ++nt) {
            const short* vrow = vb + (size_t)(nt * 16 + lr) * VT_R;
            short8 bv0 = *reinterpret_cast<const short8*>(vrow + vr0);
            short8 bv1 = *reinterpret_cast<const short8*>(vrow + vr1);
            o[nt] = __builtin_amdgcn_mfma_f32_16x16x32_bf16(ap0, bv0, o[nt], 0, 0, 0);
            o[nt] = __builtin_amdgcn_mfma_f32_16x16x32_bf16(ap1, bv1, o[nt], 0, 0, 0);
        }
    }

    // epilogue: O[q=lg*4+r][dim=nt*16+lr] / l, remap to [cls, query, doc]
    float li[4];
    for (int r = 0; r < 4; ++r) li[r] = __shfl(l_i, lg * 4 + r);
    for (int r = 0; r < 4; ++r) {
        int t = qt * 64 + wave * 16 + lg * 4 + r;
        if (t >= SEQ) continue;
        int seq = t < 512 ? 33 + t : (t == 512 ? 0 : t - 512);
        float inv = 1.f / li[r];
        float* op = out + ((size_t)(bd * SEQ + seq)) * HID + h * HD + lr;
        for (int nt = 0; nt < 4; ++nt)
            op[nt * 16] = o[nt][r] * inv;
    }
}

// ---------------------------------------------------------------------------
// Workspace (bf16 elems, seg = 16512*768 = 12.68M):
//   X @0, Qb @seg, Kb @2seg, Vt @3seg (2*768*8256 == seg). Wb -> d_out head.
// ---------------------------------------------------------------------------
extern "C" void kernel_launch(void* const* d_in, const int* in_sizes, int n_in,
                              void* d_out, int out_size, void* d_ws, size_t ws_size,
                              hipStream_t stream)
{
    const float* cls   = (const float*)d_in[0];
    const float* query = (const float*)d_in[1];
    const float* doc   = (const float*)d_in[2];
    const float* qmask = (const float*)d_in[3];
    const float* dmask = (const float*)d_in[4];
    const float* Wq = (const float*)d_in[5];
    const float* bq = (const float*)d_in[6];
    const float* Wk = (const float*)d_in[7];
    const float* bk = (const float*)d_in[8];
    const float* Wv = (const float*)d_in[9];
    const float* bv = (const float*)d_in[10];
    float* out = (float*)d_out;

    short* X  = (short*)d_ws;
    size_t seg = (size_t)PAD_ROWS * HID;
    short* Qb = X + seg;
    short* Kb = Qb + seg;
    short* Vt = Kb + seg;
    short* Wb = (short*)d_out;   // 3.54MB scratch; fully overwritten by attn2

    pack_kernel<<<dim3((PAD_ROWS * HID / 4) / 256), 256, 0, stream>>>(cls, query, doc, X);
    wpack_kernel<<<dim3((3 * WSZ / 4) / 256), 256, 0, stream>>>(Wq, Wk, Wv, Wb);
    proj_gemm2<<<dim3(PAD_ROWS / 128, HID / 128, 3), 256, 0, stream>>>(
        X, Wb, bq, bk, bv, Qb, Kb, Vt);
    attn2<<<dim3(9, NH, B_ * D_), 256, 0, stream>>>(Qb, Kb, Vt, qmask, dmask, out);
}